// Round 1
// baseline (2133.342 us; speedup 1.0000x reference)
//
#include <hip/hip_runtime.h>
#include <hip/hip_bf16.h>

typedef __attribute__((ext_vector_type(8))) short short8;       // 8 bf16 = 4 VGPR (MFMA frag)
typedef __attribute__((ext_vector_type(4))) float f32x4;        // MFMA acc
typedef __attribute__((ext_vector_type(4))) unsigned short u16x4;
typedef __attribute__((ext_vector_type(8))) unsigned short u16x8;

#define BM 128
#define BN 128
#define BK 64
#define LDK 72   // 64 + 8 pad: row stride 144B = 9*16B -> rows stay 16B-aligned, max 2-way bank alias (free)

static __device__ __forceinline__ unsigned short f2bf(float f) {
  // round-to-nearest-even fp32 -> bf16
  union { float f; unsigned int u; } c; c.f = f;
  unsigned int u = c.u;
  u += 0x7FFFu + ((u >> 16) & 1u);
  return (unsigned short)(u >> 16);
}

static __device__ __forceinline__ f32x4 mfma_bf16(short8 a, short8 b, f32x4 c) {
  return __builtin_amdgcn_mfma_f32_16x16x32_bf16(a, b, c, 0, 0, 0);
}

// ---------------------------------------------------------------------------
// Kernel 1: fused gate+up GEMM + SwiGLU.
//   g = x @ w1^T, u = x @ w3^T  (w dequantized by per-128x128 block scale)
//   h = silu(g) * u   -> bf16, row-major [M][N]
// x: [M][K] fp32, w1/w3: [N][K] fp32 (quantized values), scales [N/128][K/128]
// ---------------------------------------------------------------------------
__global__ __launch_bounds__(256, 2)
void k_gateup(const float* __restrict__ x,
              const float* __restrict__ w1, const float* __restrict__ w1s,
              const float* __restrict__ w3, const float* __restrict__ w3s,
              unsigned short* __restrict__ h,
              int M, int N, int K) {
  __shared__ unsigned short sA[BM][LDK];
  __shared__ unsigned short sB1[BM][LDK];
  __shared__ unsigned short sB3[BM][LDK];

  const int t    = threadIdx.x;
  const int bn   = blockIdx.x;
  const int bm   = blockIdx.y;
  const int lane = t & 63;
  const int wm   = (t >> 6) >> 1;   // wave row (0..1)
  const int wn   = (t >> 6) & 1;    // wave col (0..1)
  const int lr   = lane & 15;
  const int kg   = lane >> 4;       // k-group 0..3

  f32x4 accg[4][4], accu[4][4];
  #pragma unroll
  for (int i = 0; i < 4; ++i)
    #pragma unroll
    for (int j = 0; j < 4; ++j)
      #pragma unroll
      for (int e = 0; e < 4; ++e) { accg[i][j][e] = 0.0f; accu[i][j][e] = 0.0f; }

  // staging geometry: 2048 float4 per 128x64 fp32 tile, 256 threads -> 8 iters
  const int sc  = (t & 15) << 2;    // col (floats) within tile, fixed
  const int sr0 = t >> 4;           // row base, +16 per iter
  const int KB  = K >> 7;           // K/128 scale blocks

  const float* pA = x  + (size_t)(bm * BM + sr0) * K + sc;
  const float* p1 = w1 + (size_t)(bn * BN + sr0) * K + sc;
  const float* p3 = w3 + (size_t)(bn * BN + sr0) * K + sc;

  for (int kt = 0; kt < K; kt += BK) {
    const float s1 = w1s[bn * KB + (kt >> 7)];
    const float s3 = w3s[bn * KB + (kt >> 7)];
    #pragma unroll
    for (int i = 0; i < 8; ++i) {
      const int r = sr0 + i * 16;
      const size_t go = (size_t)i * 16 * K + kt;
      f32x4 va = *(const f32x4*)(pA + go);
      f32x4 v1 = *(const f32x4*)(p1 + go);
      f32x4 v3 = *(const f32x4*)(p3 + go);
      u16x4 qa, q1, q3;
      #pragma unroll
      for (int e = 0; e < 4; ++e) {
        qa[e] = f2bf(va[e]);
        q1[e] = f2bf(v1[e] * s1);
        q3[e] = f2bf(v3[e] * s3);
      }
      *(u16x4*)(&sA[r][sc])  = qa;
      *(u16x4*)(&sB1[r][sc]) = q1;
      *(u16x4*)(&sB3[r][sc]) = q3;
    }
    __syncthreads();

    #pragma unroll
    for (int ks = 0; ks < 2; ++ks) {
      const int ko = ks * 32 + kg * 8;
      short8 af[4], b1f[4], b3f[4];
      #pragma unroll
      for (int mi = 0; mi < 4; ++mi)
        af[mi] = *(const short8*)(&sA[wm * 64 + mi * 16 + lr][ko]);
      #pragma unroll
      for (int ni = 0; ni < 4; ++ni) {
        b1f[ni] = *(const short8*)(&sB1[wn * 64 + ni * 16 + lr][ko]);
        b3f[ni] = *(const short8*)(&sB3[wn * 64 + ni * 16 + lr][ko]);
      }
      #pragma unroll
      for (int mi = 0; mi < 4; ++mi)
        #pragma unroll
        for (int ni = 0; ni < 4; ++ni) {
          accg[mi][ni] = mfma_bf16(af[mi], b1f[ni], accg[mi][ni]);
          accu[mi][ni] = mfma_bf16(af[mi], b3f[ni], accu[mi][ni]);
        }
    }
    __syncthreads();
  }

  // epilogue: C/D layout col=lane&15, row=(lane>>4)*4+j  [m89-verified]
  const int r0 = bm * BM + wm * 64 + kg * 4;
  const int c0 = bn * BN + wn * 64 + lr;
  #pragma unroll
  for (int mi = 0; mi < 4; ++mi)
    #pragma unroll
    for (int ni = 0; ni < 4; ++ni)
      #pragma unroll
      for (int j = 0; j < 4; ++j) {
        const float g  = accg[mi][ni][j];
        const float u  = accu[mi][ni][j];
        const float sg = g / (1.0f + __expf(-g));   // silu
        h[(size_t)(r0 + mi * 16 + j) * N + (c0 + ni * 16)] = f2bf(sg * u);
      }
}

// ---------------------------------------------------------------------------
// Kernel 2: y = h @ w2^T  (w2 dequantized), y fp32 [M][N]
// h: [M][K] bf16, w2: [N][K] fp32, w2s: [N/128][K/128]
// ---------------------------------------------------------------------------
__global__ __launch_bounds__(256, 2)
void k_down(const unsigned short* __restrict__ h,
            const float* __restrict__ w2, const float* __restrict__ w2s,
            float* __restrict__ y,
            int M, int N, int K) {
  __shared__ unsigned short sA[BM][LDK];
  __shared__ unsigned short sB[BM][LDK];

  const int t    = threadIdx.x;
  const int bn   = blockIdx.x;
  const int bm   = blockIdx.y;
  const int lane = t & 63;
  const int wm   = (t >> 6) >> 1;
  const int wn   = (t >> 6) & 1;
  const int lr   = lane & 15;
  const int kg   = lane >> 4;

  f32x4 acc[4][4];
  #pragma unroll
  for (int i = 0; i < 4; ++i)
    #pragma unroll
    for (int j = 0; j < 4; ++j)
      #pragma unroll
      for (int e = 0; e < 4; ++e) acc[i][j][e] = 0.0f;

  // A (bf16) staging: 1024 x 16B per 128x64 tile -> 4 iters
  const int ac  = (t & 7) << 3;     // bf16 col
  const int ar0 = t >> 3;           // +32 per iter
  // B (fp32) staging: 8 iters of float4
  const int sc  = (t & 15) << 2;
  const int sr0 = t >> 4;
  const int KB  = K >> 7;

  const unsigned short* pA = h + (size_t)(bm * BM + ar0) * K + ac;
  const float* pB = w2 + (size_t)(bn * BN + sr0) * K + sc;

  for (int kt = 0; kt < K; kt += BK) {
    const float s2 = w2s[bn * KB + (kt >> 7)];
    #pragma unroll
    for (int i = 0; i < 4; ++i) {
      u16x8 v = *(const u16x8*)(pA + (size_t)i * 32 * K + kt);
      *(u16x8*)(&sA[ar0 + i * 32][ac]) = v;
    }
    #pragma unroll
    for (int i = 0; i < 8; ++i) {
      f32x4 v = *(const f32x4*)(pB + (size_t)i * 16 * K + kt);
      u16x4 q;
      #pragma unroll
      for (int e = 0; e < 4; ++e) q[e] = f2bf(v[e] * s2);
      *(u16x4*)(&sB[sr0 + i * 16][sc]) = q;
    }
    __syncthreads();

    #pragma unroll
    for (int ks = 0; ks < 2; ++ks) {
      const int ko = ks * 32 + kg * 8;
      short8 af[4], bf[4];
      #pragma unroll
      for (int mi = 0; mi < 4; ++mi)
        af[mi] = *(const short8*)(&sA[wm * 64 + mi * 16 + lr][ko]);
      #pragma unroll
      for (int ni = 0; ni < 4; ++ni)
        bf[ni] = *(const short8*)(&sB[wn * 64 + ni * 16 + lr][ko]);
      #pragma unroll
      for (int mi = 0; mi < 4; ++mi)
        #pragma unroll
        for (int ni = 0; ni < 4; ++ni)
          acc[mi][ni] = mfma_bf16(af[mi], bf[ni], acc[mi][ni]);
    }
    __syncthreads();
  }

  const int r0 = bm * BM + wm * 64 + kg * 4;
  const int c0 = bn * BN + wn * 64 + lr;
  #pragma unroll
  for (int mi = 0; mi < 4; ++mi)
    #pragma unroll
    for (int ni = 0; ni < 4; ++ni)
      #pragma unroll
      for (int j = 0; j < 4; ++j)
        y[(size_t)(r0 + mi * 16 + j) * N + (c0 + ni * 16)] = acc[mi][ni][j];
}

extern "C" void kernel_launch(void* const* d_in, const int* in_sizes, int n_in,
                              void* d_out, int out_size, void* d_ws, size_t ws_size,
                              hipStream_t stream) {
  const float* x   = (const float*)d_in[0];
  const float* w1  = (const float*)d_in[1];
  const float* w1s = (const float*)d_in[2];
  const float* w3  = (const float*)d_in[3];
  const float* w3s = (const float*)d_in[4];
  const float* w2  = (const float*)d_in[5];
  const float* w2s = (const float*)d_in[6];
  float* y = (float*)d_out;

  const int D = 4096, I = 14336;
  const int T = in_sizes[0] / D;          // 2048

  unsigned short* h = (unsigned short*)d_ws;   // [T][I] bf16 = 58.7 MB

  k_gateup<<<dim3(I / BN, T / BM), dim3(256), 0, stream>>>(x, w1, w1s, w3, w3s, h, T, I, D);
  k_down  <<<dim3(D / BN, T / BM), dim3(256), 0, stream>>>(h, w2, w2s, y, T, D, I);
}